// Round 7
// baseline (683.196 us; speedup 1.0000x reference)
//
#include <hip/hip_runtime.h>
#include <hip/hip_bf16.h>

// Bahdanau additive attention, MI355X. B=32, S=2048, E=D=1024. M = B*S = 65536.
// scores[m] = v . tanh(enc[m,:] @ w1 + qq[b]),  qq[b] = dec[b] @ w2 + b2 + b1
// (bv dropped: softmax-invariant). attn = softmax_s(scores); context[b] = attn[b,:] @ enc[b,:,:]
//
// Round-7: (1) GEMM goes 128x256 tile / 512 threads — halves per-thread
// A-staging (load+convert) and halves A HBM traffic; barriers can't span
// global loads on gfx950 (r2/r5/r6 evidence), so shrink staging instead of
// pipelining it. (2) Aux fused: 6 dispatches -> 3 (prep = pack_w1 + qq +
// zero-scores; softmax recomputed per ctx block from an 8KB scores read).
// LDS image per 128-row x 64-col bf16 tile: rows of 128B = 8 chunks of 16B,
// logical chunk c stored at c ^ (row & 7) — conflict-free for ds_write_b128
// staging and ds_read_b128 frags (SQ_LDS_BANK_CONFLICT == 0, rounds 2-6).

typedef __attribute__((ext_vector_type(8))) short short8;   // 8 bf16 (4 VGPRs)
typedef __attribute__((ext_vector_type(4))) float f32x4;    // MFMA acc

#define M_TOTAL 65536
#define KDIM    1024
#define KT_N    16          // KDIM / 64

// pack two fp32 -> two bf16 (round-half-up) in one dword: 2 adds + 1 v_perm
static __device__ inline unsigned int pk2h(float a, float b) {
    unsigned int ua = __builtin_bit_cast(unsigned int, a) + 0x8000u;
    unsigned int ub = __builtin_bit_cast(unsigned int, b) + 0x8000u;
    return __builtin_amdgcn_perm(ub, ua, 0x07060302u);
}

static __device__ inline void async_copy16(const void* g, void* l) {
    __builtin_amdgcn_global_load_lds(
        (const __attribute__((address_space(1))) unsigned int*)g,
        (__attribute__((address_space(3))) unsigned int*)l, 16, 0, 0);
}

// ---- fused prep: pack_w1 (blocks 0..1023) + qq (1024..1055) + zero scores ----
// w1p layout (N-tiles of 256): w1p[(nt*16+kc)*16384 + r*64 + (c^(r&7))*8 + j]
//   nt = e>>8, r = e&255, kc = d>>6, c = (d>>3)&7, j = d&7
__global__ __launch_bounds__(256) void prep(const float* __restrict__ w1,
                                            unsigned short* __restrict__ w1p,
                                            const float* __restrict__ dec,
                                            const float* __restrict__ w2,
                                            const float* __restrict__ b1,
                                            const float* __restrict__ b2,
                                            float* __restrict__ qq,
                                            float* __restrict__ scores) {
    const int blk = blockIdx.x;
    const int t = threadIdx.x;
    if (blk < 1024) {
        // transpose+convert one 32x32 tile of w1
        __shared__ float tile[32][33];
        const int bx = blk & 31, by = blk >> 5;   // e-tile, d-tile
        const int col = t & 31, rq = t >> 5;
#pragma unroll
        for (int q = 0; q < 4; q++) {
            const int row = rq * 4 + q;
            tile[row][col] = w1[(by * 32 + row) * 1024 + bx * 32 + col];
        }
        __syncthreads();
#pragma unroll
        for (int q = 0; q < 4; q++) {
            const int ty = rq * 4 + q;
            const int eo = bx * 32 + ty;          // n-dim
            const int dq = by * 32 + col;         // k-dim
            const unsigned int u = __builtin_bit_cast(unsigned int, tile[col][ty]) + 0x8000u;
            const unsigned short us = (unsigned short)(u >> 16);
            const int nt = eo >> 8, r = eo & 255;
            const int kc = dq >> 6, c = (dq >> 3) & 7, j = dq & 7;
            const int cs = c ^ (r & 7);
            w1p[(((size_t)(nt * 16 + kc)) << 14) + (r << 6) + (cs << 3) + j] = us;
        }
    } else if (blk < 1056) {
        // qq[b][e] = b1[e]+b2[e] + dec[b]@w2[:,e]; 32 e-chunks, 8 b per thread-group
        const int ec = blk - 1024;
        const int e = ec * 32 + (t & 31);
        const int b0 = t >> 5;                    // 0..7
        float acc[4] = {0.f, 0.f, 0.f, 0.f};
#pragma unroll 4
        for (int d = 0; d < 1024; d++) {
            const float w2v = w2[d * 1024 + e];
#pragma unroll
            for (int i = 0; i < 4; i++)
                acc[i] = fmaf(dec[(b0 + 8 * i) * 1024 + d], w2v, acc[i]);
        }
        const float bias = b1[e] + b2[e];
#pragma unroll
        for (int i = 0; i < 4; i++)
            qq[(b0 + 8 * i) * 1024 + e] = acc[i] + bias;
    } else {
        // zero scores: 64 blocks x 1024 floats
        const int z = blk - 1056;
        const float4 zero = {0.f, 0.f, 0.f, 0.f};
        *reinterpret_cast<float4*>(scores + z * 1024 + t * 4) = zero;
    }
}

// ---- fused GEMM: 128x256 tile, BK=64, 512 threads (2m x 4n wave grid) ----
__global__ __launch_bounds__(512) void score_gemm(const float* __restrict__ enc,
                                                  const unsigned short* __restrict__ w1p,
                                                  const float* __restrict__ qq,
                                                  const float* __restrict__ vvec,
                                                  float* __restrict__ scores) {
    __shared__ __align__(16) unsigned short As[128 * 64];   // 16KB
    __shared__ __align__(16) unsigned short Bs[256 * 64];   // 32KB

    // XCD swizzle: the 4 n-blocks of one m-strip land on the same XCD
    const int g = blockIdx.x;                    // 0..2047
    const int mtile = (g >> 5) * 8 + (g & 7);    // 0..511
    const int ntile = (g >> 3) & 3;              // 0..3
    const int m0 = mtile * 128;
    const int b = m0 >> 11;

    const int tid = threadIdx.x;
    const int wid = tid >> 6;
    const int lane = tid & 63;
    const int wm = wid >> 2, wn = wid & 3;       // 2x4 wave grid, 64x64 each
    const int quad = lane >> 4, lc = lane & 15;
    const int swz = lc & 7;                      // row&7 for rows i*16+lc
    const int fc0 = ((quad ^ swz) << 3);         // khalf 0 chunk offset
    const int fc1 = (((4 + quad) ^ swz) << 3);   // khalf 1

    // A staging: thread -> row r = tid>>2 (0..127), quarter u = tid&3 (16 elems)
    const int r = tid >> 2, u = tid & 3;
    const int aw0_off = (r << 6) + (((2 * u) ^ (r & 7)) << 3);
    const int aw1_off = (r << 6) + (((2 * u + 1) ^ (r & 7)) << 3);

    f32x4 acc[4][4];
#pragma unroll
    for (int mi = 0; mi < 4; mi++)
#pragma unroll
        for (int ni = 0; ni < 4; ni++)
            acc[mi][ni] = (f32x4){0.f, 0.f, 0.f, 0.f};

    // B DMA: 8 waves x 4KB of the 32KB (256x64) image per kt
    const unsigned short* bbase = w1p + ((size_t)ntile << 18) + (wid << 11) + (lane << 3);
    unsigned short* bdst = &Bs[wid << 11];
    const float* abase = enc + (size_t)(m0 + r) * 1024 + u * 16;

    for (int kt = 0; kt < KT_N; kt++) {
        __syncthreads();   // prior iteration's LDS reads done

        // B: pure DMA (w1p pre-packed in LDS-image order)
        const unsigned short* bsrc = bbase + ((size_t)kt << 14);
        async_copy16(bsrc, bdst);
        async_copy16(bsrc + 512, bdst + 512);
        async_copy16(bsrc + 1024, bdst + 1024);
        async_copy16(bsrc + 1536, bdst + 1536);

        // A: 16 fp32 per thread (4 loads, 8 pk2h, 2 ds_writes)
        const float* asrc = abase + kt * 64;
        const float4 f0 = *reinterpret_cast<const float4*>(asrc);
        const float4 f1 = *reinterpret_cast<const float4*>(asrc + 4);
        const float4 f2 = *reinterpret_cast<const float4*>(asrc + 8);
        const float4 f3 = *reinterpret_cast<const float4*>(asrc + 12);
        uint4 w0, w1v;
        w0.x = pk2h(f0.x, f0.y); w0.y = pk2h(f0.z, f0.w);
        w0.z = pk2h(f1.x, f1.y); w0.w = pk2h(f1.z, f1.w);
        w1v.x = pk2h(f2.x, f2.y); w1v.y = pk2h(f2.z, f2.w);
        w1v.z = pk2h(f3.x, f3.y); w1v.w = pk2h(f3.z, f3.w);
        *reinterpret_cast<uint4*>(&As[aw0_off]) = w0;
        *reinterpret_cast<uint4*>(&As[aw1_off]) = w1v;

        __syncthreads();   // drains B-DMA + A ds_writes

        short8 af[4], bf[4];
#pragma unroll
        for (int i = 0; i < 4; i++) {
            af[i] = *reinterpret_cast<const short8*>(&As[((wm * 64 + i * 16 + lc) << 6) + fc0]);
            bf[i] = *reinterpret_cast<const short8*>(&Bs[((wn * 64 + i * 16 + lc) << 6) + fc0]);
        }
#pragma unroll
        for (int mi = 0; mi < 4; mi++)
#pragma unroll
            for (int ni = 0; ni < 4; ni++)
                acc[mi][ni] = __builtin_amdgcn_mfma_f32_16x16x32_bf16(af[mi], bf[ni], acc[mi][ni], 0, 0, 0);
#pragma unroll
        for (int i = 0; i < 4; i++) {
            af[i] = *reinterpret_cast<const short8*>(&As[((wm * 64 + i * 16 + lc) << 6) + fc1]);
            bf[i] = *reinterpret_cast<const short8*>(&Bs[((wn * 64 + i * 16 + lc) << 6) + fc1]);
        }
#pragma unroll
        for (int mi = 0; mi < 4; mi++)
#pragma unroll
            for (int ni = 0; ni < 4; ni++)
                acc[mi][ni] = __builtin_amdgcn_mfma_f32_16x16x32_bf16(af[mi], bf[ni], acc[mi][ni], 0, 0, 0);
    }

    // epilogue: tanh(C + qq[b][n]) * v[n], quad butterfly, atomic into scores
    const float* qqb = qq + b * 1024;
    const int nb = ntile * 256 + wn * 64 + lc;
    float qn[4], vn[4];
#pragma unroll
    for (int ni = 0; ni < 4; ni++) {
        qn[ni] = qqb[nb + ni * 16];
        vn[ni] = vvec[nb + ni * 16];
    }
    float red[16];
#pragma unroll
    for (int mi = 0; mi < 4; mi++) {
#pragma unroll
        for (int rr = 0; rr < 4; rr++) {
            float ssum = 0.f;
#pragma unroll
            for (int ni = 0; ni < 4; ni++) {
                float x = acc[mi][ni][rr] + qn[ni];
                float e = __expf(2.0f * x);          // overflow-safe tanh
                float th = 1.0f - 2.0f / (e + 1.0f);
                ssum = fmaf(th, vn[ni], ssum);
            }
            float tt = ssum;
            tt += __shfl_xor(tt, 1);
            tt += __shfl_xor(tt, 2);
            tt += __shfl_xor(tt, 4);
            tt += __shfl_xor(tt, 8);
            red[mi * 4 + rr] = tt;
        }
    }
    float myv = red[0];
#pragma unroll
    for (int i = 1; i < 16; i++)
        if (lc == i) myv = red[i];
    atomicAdd(scores + m0 + wm * 64 + (lc >> 2) * 16 + quad * 4 + (lc & 3), myv);
}

// ---- fused softmax + context: 256 blocks (8 e-chunks x 32 batches) ----
// Each block recomputes softmax stats from scores (8KB read, cheap) -> LDS
// attn, then context for its 128-e slice. No attn array, no atomics on out.
__global__ __launch_bounds__(256) void ctx_softmax(const float* __restrict__ scores,
                                                   const float* __restrict__ enc,
                                                   float* __restrict__ out) {
    const int ec = blockIdx.x, b = blockIdx.y;
    const int t = threadIdx.x;
    const int lane = t & 63, wid = t >> 6;
    __shared__ float attn[2048];
    __shared__ float redm[4], reds[4];
    __shared__ float4 redc[8][32];

    const float* s = scores + b * 2048;
    float x[8];
    float m = -1e30f;
#pragma unroll
    for (int i = 0; i < 8; i++) {
        x[i] = s[t + i * 256];
        m = fmaxf(m, x[i]);
    }
    for (int o = 1; o < 64; o <<= 1) m = fmaxf(m, __shfl_xor(m, o));
    if (lane == 0) redm[wid] = m;
    __syncthreads();
    m = fmaxf(fmaxf(redm[0], redm[1]), fmaxf(redm[2], redm[3]));
    float sum = 0.f;
#pragma unroll
    for (int i = 0; i < 8; i++) {
        x[i] = __expf(x[i] - m);
        sum += x[i];
    }
    for (int o = 1; o < 64; o <<= 1) sum += __shfl_xor(sum, o);
    if (lane == 0) reds[wid] = sum;
    __syncthreads();
    const float inv = 1.0f / (reds[0] + reds[1] + reds[2] + reds[3]);
#pragma unroll
    for (int i = 0; i < 8; i++) attn[t + i * 256] = x[i] * inv;
    __syncthreads();

    // context: thread -> e-float4 (t&31), s-slice (t>>5) of 256
    const int e0 = ec * 128 + (t & 31) * 4;
    const int sl = t >> 5;
    const float* eb = enc + ((size_t)b * 2048 + sl * 256) * 1024 + e0;
    const float* aw = attn + sl * 256;
    float4 acc = {0.f, 0.f, 0.f, 0.f};
#pragma unroll 8
    for (int si = 0; si < 256; si++) {
        const float w = aw[si];
        const float4 ev = *reinterpret_cast<const float4*>(eb + (size_t)si * 1024);
        acc.x = fmaf(w, ev.x, acc.x);
        acc.y = fmaf(w, ev.y, acc.y);
        acc.z = fmaf(w, ev.z, acc.z);
        acc.w = fmaf(w, ev.w, acc.w);
    }
    redc[sl][t & 31] = acc;
    __syncthreads();
    if (t < 32) {
        float4 a = redc[0][t];
#pragma unroll
        for (int i = 1; i < 8; i++) {
            const float4 v = redc[i][t];
            a.x += v.x; a.y += v.y; a.z += v.z; a.w += v.w;
        }
        *reinterpret_cast<float4*>(out + b * 1024 + ec * 128 + t * 4) = a;
    }
}

extern "C" void kernel_launch(void* const* d_in, const int* in_sizes, int n_in,
                              void* d_out, int out_size, void* d_ws, size_t ws_size,
                              hipStream_t stream) {
    const float* enc = (const float*)d_in[0];  // 32*2048*1024
    const float* dec = (const float*)d_in[1];  // 32*1*1024
    const float* w1  = (const float*)d_in[2];  // 1024*1024
    const float* b1  = (const float*)d_in[3];  // 1024
    const float* w2  = (const float*)d_in[4];  // 1024*1024
    const float* b2  = (const float*)d_in[5];  // 1024
    const float* v   = (const float*)d_in[6];  // 1024
    // d_in[7] = bv, softmax-invariant, unused
    float* out = (float*)d_out;                // 32*1024

    char* ws = (char*)d_ws;
    unsigned short* w1p = (unsigned short*)ws;                 // 2 MB
    float* qq     = (float*)(ws + (2u << 20));                 // 128 KB
    float* scores = (float*)(ws + (2u << 20) + (128u << 10));  // 256 KB
    // total ws need: ~2.4 MB

    prep<<<1120, 256, 0, stream>>>(w1, w1p, dec, w2, b1, b2, qq, scores);
    score_gemm<<<2048, 512, 0, stream>>>(enc, w1p, qq, v, scores);
    ctx_softmax<<<dim3(8, 32), 256, 0, stream>>>(scores, enc, out);
}